// Round 7
// baseline (523.589 us; speedup 1.0000x reference)
//
#include <hip/hip_runtime.h>
#include <stdint.h>

#define NSCENE 16
#define NPED 32
#define NB_TOT 512
#define HD 64
#define ED 64
#define D1 8192
#define BOTN 1024
#define ASTR 72  // A-tile LDS row stride in shorts (144B): 16B-aligned, bank-rotating

typedef unsigned short ushort_t;
typedef __attribute__((ext_vector_type(4))) float f32x4;
typedef __attribute__((ext_vector_type(8))) __bf16 bf16x8;  // gfx950 mfma operand (V8y)
typedef __attribute__((ext_vector_type(4))) unsigned int u32x4;
typedef __attribute__((ext_vector_type(2))) unsigned int u32x2;

__device__ __forceinline__ float bf2f(ushort_t u) {
  union { unsigned int i; float f; } x;
  x.i = ((unsigned int)u) << 16;
  return x.f;
}

__device__ __forceinline__ ushort_t f2bf(float f) {
  union { float f; unsigned int i; } x;
  x.f = f;
  unsigned int u = x.i + 0x7fffu + ((x.i >> 16) & 1u);
  return (ushort_t)(u >> 16);
}

// pack two f32 -> two bf16 RNE (lo in bits [15:0])
__device__ __forceinline__ unsigned int packbf(float lo, float hi) {
#if __has_builtin(__builtin_amdgcn_cvt_pk_bf16_f32)
  typedef __attribute__((ext_vector_type(2))) __bf16 bf16x2_t;
  union { bf16x2_t v; unsigned int u; } x;
  x.v = __builtin_amdgcn_cvt_pk_bf16_f32(lo, hi);
  return x.u;
#else
  return (unsigned int)f2bf(lo) | ((unsigned int)f2bf(hi) << 16);
#endif
}

// async global->LDS DMA, 16B/lane; casts through integers (legal reinterpret).
// HW: LDS dest = wave-uniform base + lane*16 — caller arranges that.
__device__ __forceinline__ void async_load16(const void* g, void* l) {
  __builtin_amdgcn_global_load_lds(
      (const __attribute__((address_space(1))) unsigned int*)(unsigned long long)g,
      (__attribute__((address_space(3))) unsigned int*)(unsigned int)(unsigned long long)l,
      16, 0, 0);
}

// ---------------------------------------------------------------------------
// k_detect: decide whether float inputs are fp32 (expected) or bf16.
// Also produce canonical fp32 copies of end_pos and b2.
// ---------------------------------------------------------------------------
__global__ __launch_bounds__(256) void k_detect(
    const void* __restrict__ W1v, const void* __restrict__ end_posv,
    const void* __restrict__ b2v, int* __restrict__ flag,
    float* __restrict__ epf, float* __restrict__ b2f) {
  __shared__ int cnt[256];
  __shared__ int isbf_s;
  const int t = threadIdx.x;
  const ushort_t* wu = (const ushort_t*)W1v;
  unsigned int u = wu[2 * t];
  int e = (u >> 7) & 0xff;
  cnt[t] = (e >= 90 && e <= 140) ? 1 : 0;
  __syncthreads();
  for (int ofs = 128; ofs > 0; ofs >>= 1) {
    if (t < ofs) cnt[t] += cnt[t + ofs];
    __syncthreads();
  }
  if (t == 0) {
    isbf_s = (cnt[0] >= 128) ? 1 : 0;
    *flag = isbf_s;
  }
  __syncthreads();
  const int isbf = isbf_s;
  const ushort_t* epu = (const ushort_t*)end_posv;
  const float* epff = (const float*)end_posv;
  const ushort_t* b2u = (const ushort_t*)b2v;
  const float* b2ff = (const float*)b2v;
  for (int i = t; i < 1024; i += 256) {
    epf[i] = isbf ? bf2f(epu[i]) : epff[i];
    b2f[i] = isbf ? bf2f(b2u[i]) : b2ff[i];
  }
}

// ---------------------------------------------------------------------------
// k_prep: M0[k] = sum_e Wsp[0][e]*W1[e][k]; M1 likewise;
//         hbias[k] = b1[k] + sum_e bsp[e]*W1[e][k]
// ---------------------------------------------------------------------------
__global__ __launch_bounds__(256) void k_prep(
    const void* __restrict__ W_spv, const void* __restrict__ b_spv,
    const void* __restrict__ W1v, const void* __restrict__ b1v,
    const int* __restrict__ flag,
    float* __restrict__ M0, float* __restrict__ M1, float* __restrict__ hbias) {
  const int isbf = *flag;
  const ushort_t* Wspu = (const ushort_t*)W_spv;
  const float* Wspf = (const float*)W_spv;
  const ushort_t* bspu = (const ushort_t*)b_spv;
  const float* bspf = (const float*)b_spv;
  const ushort_t* W1u = (const ushort_t*)W1v;
  const float* W1f = (const float*)W1v;
  const ushort_t* b1u = (const ushort_t*)b1v;
  const float* b1f = (const float*)b1v;
  int k = blockIdx.x * 256 + threadIdx.x;
  float m0 = 0.f, m1 = 0.f, hb = 0.f;
  for (int e = 0; e < ED; ++e) {
    float w = isbf ? bf2f(W1u[e * D1 + k]) : W1f[e * D1 + k];
    float s0 = isbf ? bf2f(Wspu[e]) : Wspf[e];
    float s1 = isbf ? bf2f(Wspu[ED + e]) : Wspf[ED + e];
    float bs = isbf ? bf2f(bspu[e]) : bspf[e];
    m0 += s0 * w;
    m1 += s1 * w;
    hb += bs * w;
  }
  M0[k] = m0;
  M1[k] = m1;
  hbias[k] = hb + (isbf ? bf2f(b1u[k]) : b1f[k]);
}

// ---------------------------------------------------------------------------
// k_hc v2: hc[j][k] = hbias[k] + sum_h h[j][hh]*W1[64+hh][k]  (bf16 out)
// grid (8 kt, 32 jt), 256 thr: block = 16 j-rows x 1024 k; thread = 16j x 4k.
// W1 slice read ONCE per block (16x reuse vs v1); h reads are wave-uniform
// (s_load broadcast). VALU-bound ~4096 fma/thread.
// ---------------------------------------------------------------------------
__global__ __launch_bounds__(256) void k_hc(
    const void* __restrict__ hv_, const void* __restrict__ W1v,
    const float* __restrict__ hbias, const int* __restrict__ flag,
    ushort_t* __restrict__ hcb) {
  const int isbf = *flag;
  const int kb = blockIdx.x;  // 0..7
  const int jt = blockIdx.y;  // 0..31
  const int t = threadIdx.x;
  const int kbase = kb * 1024 + t * 4;
  float acc[16][4];
#pragma unroll
  for (int j = 0; j < 16; ++j)
#pragma unroll
    for (int c = 0; c < 4; ++c) acc[j][c] = 0.f;

  if (isbf) {
    const ushort_t* wp = (const ushort_t*)W1v + (size_t)ED * D1 + kbase;
    const ushort_t* hp = (const ushort_t*)hv_ + jt * 16 * HD;
    for (int hh = 0; hh < HD; ++hh) {
      u32x2 wv = *(const u32x2*)(wp + (size_t)hh * D1);
      float w0 = bf2f((ushort_t)(wv.x & 0xffffu)), w1 = bf2f((ushort_t)(wv.x >> 16));
      float w2 = bf2f((ushort_t)(wv.y & 0xffffu)), w3 = bf2f((ushort_t)(wv.y >> 16));
#pragma unroll
      for (int j = 0; j < 16; ++j) {
        float hj = bf2f(hp[j * HD + hh]);
        acc[j][0] += hj * w0;
        acc[j][1] += hj * w1;
        acc[j][2] += hj * w2;
        acc[j][3] += hj * w3;
      }
    }
  } else {
    const float* wp = (const float*)W1v + (size_t)ED * D1 + kbase;
    const float* hp = (const float*)hv_ + jt * 16 * HD;
#pragma unroll 4
    for (int hh = 0; hh < HD; ++hh) {
      float4 w = *(const float4*)(wp + (size_t)hh * D1);
#pragma unroll
      for (int j = 0; j < 16; ++j) {
        float hj = hp[j * HD + hh];
        acc[j][0] += hj * w.x;
        acc[j][1] += hj * w.y;
        acc[j][2] += hj * w.z;
        acc[j][3] += hj * w.w;
      }
    }
  }
  float4 hb = *(const float4*)(hbias + kbase);
#pragma unroll
  for (int j = 0; j < 16; ++j) {
    u32x2 pk;
    pk.x = packbf(acc[j][0] + hb.x, acc[j][1] + hb.y);
    pk.y = packbf(acc[j][2] + hb.z, acc[j][3] + hb.w);
    *(u32x2*)(hcb + (size_t)(jt * 16 + j) * D1 + kbase) = pk;
  }
}

// ---------------------------------------------------------------------------
// k_tr: W2T[n][k] = (bf16)W2[k][n]   (8192x1024 -> 1024x8192)
// ---------------------------------------------------------------------------
__global__ __launch_bounds__(256) void k_tr(const void* __restrict__ W2v,
                                            const int* __restrict__ flag,
                                            ushort_t* __restrict__ W2T) {
  __shared__ ushort_t tile[64][72];
  const int isbf = *flag;
  int kt = blockIdx.x, nt = blockIdx.y;
  int t = threadIdx.x;
  int r = t >> 3, c8 = (t & 7) * 8;
#pragma unroll
  for (int i = 0; i < 2; ++i) {
    int row = i * 32 + r;
    size_t base = (size_t)(kt * 64 + row) * BOTN + nt * 64 + c8;
    if (isbf) {
      u32x4 v = *(const u32x4*)((const ushort_t*)W2v + base);
      *(u32x4*)&tile[row][c8] = v;
    } else {
      const float* src = (const float*)W2v + base;
      float4 w0 = *(const float4*)src;
      float4 w1 = *(const float4*)(src + 4);
      u32x4 pk;
      pk.x = packbf(w0.x, w0.y);
      pk.y = packbf(w0.z, w0.w);
      pk.z = packbf(w1.x, w1.y);
      pk.w = packbf(w1.z, w1.w);
      *(u32x4*)&tile[row][c8] = pk;
    }
  }
  __syncthreads();
#pragma unroll
  for (int i = 0; i < 2; ++i) {
    int nrow = i * 32 + r;
    union { ushort_t us[8]; u32x4 v; } pk;
#pragma unroll
    for (int jj = 0; jj < 8; ++jj) pk.us[jj] = tile[c8 + jj][nrow];
    *(u32x4*)(W2T + (size_t)(nt * 64 + nrow) * D1 + kt * 64 + c8) = pk.v;
  }
}

// ---------------------------------------------------------------------------
// k_gemm v3: fused A-gen + GEMM + max-pool epilogue
// BM=64 BN=256 BK=64; grid 1024: nb=bid&3 (XCD-aligned), mb=bid>>2 (0..255)
// 4 waves, each 64m x 64n (acc 4x4 f32x4 = 64 AGPR) -> 3 blocks/CU via
// __launch_bounds__(256,3). LDS 42.5 KB. B tile: DMA w16 into unpadded
// [256][64] with XOR swizzle on the global-fetch side.
// ---------------------------------------------------------------------------
__global__ __launch_bounds__(256, 3) void k_gemm(
    const ushort_t* __restrict__ hcb, const float* __restrict__ M0f,
    const float* __restrict__ M1f, const ushort_t* __restrict__ W2T,
    const float* __restrict__ epf, const float* __restrict__ b2f,
    const int* __restrict__ flag, void* __restrict__ outv) {
  __shared__ ushort_t aLds[64 * ASTR];   // 9.2 KB, padded
  __shared__ ushort_t bLds[256 * 64];    // 32 KB, unpadded (DMA dest), swizzled
  __shared__ float2 rrLds[64];

  const int t = threadIdx.x;
  const int w = t >> 6;
  const int lane = t & 63;
  const int nb = blockIdx.x & 3;
  const int mb = blockIdx.x >> 2;  // 0..255
  const int s = mb >> 4;
  const int abase = (mb & 15) * 2;
  const int isbf = *flag;

  if (t < 64) {
    int g = t >> 5, b = t & 31;
    int pa = s * 32 + abase + g, pb = s * 32 + b;
    float r0 = epf[pb * 2] - epf[pa * 2];
    float r1 = epf[pb * 2 + 1] - epf[pa * 2 + 1];
    r0 = fminf(fmaxf(r0, -1.f), 1.f);
    r1 = fminf(fmaxf(r1, -1.f), 1.f);
    rrLds[t] = make_float2(r0, r1);
  }
  __syncthreads();

  const int bq = t >> 3;  // 0..31 : hc row (b) this thread generates
  const int kc = t & 7;   // 0..7  : 8-short chunk within BK
  float rr0[2], rr1[2];
#pragma unroll
  for (int g = 0; g < 2; ++g) {
    float2 v = rrLds[g * 32 + bq];
    rr0[g] = v.x;
    rr1[g] = v.y;
  }

  const ushort_t* hcRow = hcb + (size_t)(s * 32 + bq) * D1 + kc * 8;
  const float* m0p = M0f + kc * 8;
  const float* m1p = M1f + kc * 8;

  // B DMA: lane covers row (i*32 + w*8 + (lane>>3)), LDS slot lane&7;
  // fetches global chunk (lane&7)^(lane>>3) so readers use slot ck^(row&7).
  const int rowl = w * 8 + (lane >> 3);
  const int chl = (lane & 7) ^ (lane >> 3);
  const ushort_t* bGlob = W2T + (size_t)(nb * 256 + rowl) * D1 + chl * 8;
  ushort_t* bLdsLane = bLds + (size_t)rowl * 64 + (lane & 7) * 8;  // base + lane*16B

  ushort_t* aW = aLds + bq * ASTR + kc * 8;  // + g*32*ASTR

  f32x4 acc[4][4];
#pragma unroll
  for (int mt = 0; mt < 4; ++mt)
#pragma unroll
    for (int nt = 0; nt < 4; ++nt) acc[mt][nt] = (f32x4){0.f, 0.f, 0.f, 0.f};

  const int rl = lane & 15, q = lane >> 4, r7 = rl & 7;
  const ushort_t* aRbase = aLds + rl * ASTR + q * 8;    // + mt*16*ASTR + ki*32
  const ushort_t* bRbase = bLds + (w * 64 + rl) * 64;   // + nt*1024 + slot*8
  const int sl0 = (q ^ r7) * 8;        // ki=0: global chunk q
  const int sl1 = ((q + 4) ^ r7) * 8;  // ki=1: global chunk q+4

  for (int kk = 0; kk < D1 / 64; ++kk) {
    const int k0 = kk * 64;
    // ---- B tile: async DMA global->LDS (16B/lane, 8 issues/wave) ----
#pragma unroll
    for (int i = 0; i < 8; ++i)
      async_load16(bGlob + (size_t)i * 32 * D1 + k0, bLdsLane + i * 32 * 64);

    // ---- A-gen: relu(hc + r0*M0 + r1*M1), pack bf16, write LDS ----
    u32x4 hv = *(const u32x4*)(hcRow + k0);
    float h0 = bf2f((ushort_t)(hv.x & 0xffffu)), h1 = bf2f((ushort_t)(hv.x >> 16));
    float h2 = bf2f((ushort_t)(hv.y & 0xffffu)), h3 = bf2f((ushort_t)(hv.y >> 16));
    float h4 = bf2f((ushort_t)(hv.z & 0xffffu)), h5 = bf2f((ushort_t)(hv.z >> 16));
    float h6 = bf2f((ushort_t)(hv.w & 0xffffu)), h7 = bf2f((ushort_t)(hv.w >> 16));
    float4 a0 = *(const float4*)(m0p + k0);
    float4 a1 = *(const float4*)(m0p + k0 + 4);
    float4 c0 = *(const float4*)(m1p + k0);
    float4 c1 = *(const float4*)(m1p + k0 + 4);
#pragma unroll
    for (int g = 0; g < 2; ++g) {
      float r0 = rr0[g], r1 = rr1[g];
      float v0 = fmaxf(h0 + r0 * a0.x + r1 * c0.x, 0.f);
      float v1 = fmaxf(h1 + r0 * a0.y + r1 * c0.y, 0.f);
      float v2 = fmaxf(h2 + r0 * a0.z + r1 * c0.z, 0.f);
      float v3 = fmaxf(h3 + r0 * a0.w + r1 * c0.w, 0.f);
      float v4 = fmaxf(h4 + r0 * a1.x + r1 * c1.x, 0.f);
      float v5 = fmaxf(h5 + r0 * a1.y + r1 * c1.y, 0.f);
      float v6 = fmaxf(h6 + r0 * a1.z + r1 * c1.z, 0.f);
      float v7 = fmaxf(h7 + r0 * a1.w + r1 * c1.w, 0.f);
      u32x4 pk;
      pk.x = packbf(v0, v1);
      pk.y = packbf(v2, v3);
      pk.z = packbf(v4, v5);
      pk.w = packbf(v6, v7);
      *(u32x4*)(aW + g * 32 * ASTR) = pk;
    }
    __syncthreads();  // drains DMA (vmcnt) + A-gen ds_writes

    // ---- mfma phase: 2 ki x (4 mt x 4 nt) ----
#pragma unroll
    for (int ki = 0; ki < 2; ++ki) {
      bf16x8 af[4], bfr[4];
#pragma unroll
      for (int mt = 0; mt < 4; ++mt)
        af[mt] = *(const bf16x8*)(aRbase + mt * 16 * ASTR + ki * 32);
      const int slk = ki ? sl1 : sl0;
#pragma unroll
      for (int nt = 0; nt < 4; ++nt)
        bfr[nt] = *(const bf16x8*)(bRbase + nt * 1024 + slk);
#pragma unroll
      for (int mt = 0; mt < 4; ++mt)
#pragma unroll
        for (int nt = 0; nt < 4; ++nt)
          acc[mt][nt] = __builtin_amdgcn_mfma_f32_16x16x32_bf16(af[mt], bfr[nt], acc[mt][nt], 0, 0, 0);
    }
    __syncthreads();
  }

  // ---- epilogue: max over b (32 m-rows/group), +b2, relu, store ----
#pragma unroll
  for (int g = 0; g < 2; ++g) {
    int orow = s * 32 + abase + g;
#pragma unroll
    for (int nt = 0; nt < 4; ++nt) {
      f32x4 x0 = acc[2 * g][nt], x1 = acc[2 * g + 1][nt];
      float v = fmaxf(fmaxf(fmaxf(x0.x, x0.y), fmaxf(x0.z, x0.w)),
                      fmaxf(fmaxf(x1.x, x1.y), fmaxf(x1.z, x1.w)));
      v = fmaxf(v, __shfl_xor(v, 16, 64));
      v = fmaxf(v, __shfl_xor(v, 32, 64));
      if (lane < 16) {
        int col = nb * 256 + w * 64 + nt * 16 + lane;
        float o = fmaxf(v + b2f[col], 0.f);
        if (isbf)
          ((ushort_t*)outv)[(size_t)orow * BOTN + col] = f2bf(o);
        else
          ((float*)outv)[(size_t)orow * BOTN + col] = o;
      }
    }
  }
}

extern "C" void kernel_launch(void* const* d_in, const int* in_sizes, int n_in,
                              void* d_out, int out_size, void* d_ws, size_t ws_size,
                              hipStream_t stream) {
  (void)in_sizes; (void)n_in; (void)out_size; (void)ws_size;
  const void* h_states = d_in[0];
  const void* end_pos = d_in[1];
  // d_in[2] rel_pos: unused by reference; d_in[3] seq_start_end: fixed equal scenes
  const void* W_sp = d_in[4];
  const void* b_sp = d_in[5];
  const void* W1 = d_in[6];
  const void* b1 = d_in[7];
  const void* W2 = d_in[8];
  const void* b2 = d_in[9];

  char* ws = (char*)d_ws;
  ushort_t* hcb = (ushort_t*)ws;                         // 8 MB  (512x8192 bf16)
  ushort_t* W2T = (ushort_t*)(ws + (8u << 20));          // 16 MB (1024x8192 bf16)
  float* M0f = (float*)(ws + (24u << 20));               // 32 KB
  float* M1f = (float*)(ws + (24u << 20) + 32768);       // 32 KB
  float* hbias = (float*)(ws + (24u << 20) + 65536);     // 32 KB
  float* epf = (float*)(ws + (24u << 20) + 98304);       // 4 KB
  float* b2f = (float*)(ws + (24u << 20) + 102400);      // 4 KB
  int* flag = (int*)(ws + (24u << 20) + 106496);         // 4 B

  k_detect<<<dim3(1), dim3(256), 0, stream>>>(W1, end_pos, b2, flag, epf, b2f);
  k_prep<<<dim3(32), dim3(256), 0, stream>>>(W_sp, b_sp, W1, b1, flag, M0f, M1f, hbias);
  k_hc<<<dim3(8, 32), dim3(256), 0, stream>>>(h_states, W1, hbias, flag, hcb);
  k_tr<<<dim3(128, 16), dim3(256), 0, stream>>>(W2, flag, W2T);
  k_gemm<<<dim3(1024), dim3(256), 0, stream>>>(hcb, M0f, M1f, W2T, epf, b2f, flag, d_out);
}